// Round 2
// baseline (16.846 us; speedup 1.0000x reference)
//
#include <hip/hip_runtime.h>
#include <stdint.h>

#define NUM_GRAPHS 8192
#define NODES_PER_GRAPH 128
#define TOTAL_NODES (NUM_GRAPHS * NODES_PER_GRAPH)
#define C 128
#define GGROUPS (NUM_GRAPHS / 16)   // 512 graph-groups of 16
#define CSPLIT 4                    // col-splits: each wave does 2 of the 8 col-tiles

typedef __attribute__((ext_vector_type(8))) short bf16x8;
typedef __attribute__((ext_vector_type(4))) float f32x4;

// f32 -> bf16 bits, round-to-nearest-even
static __device__ __forceinline__ short f2bf(float f) {
    union { float f; uint32_t u; } v; v.f = f;
    const uint32_t u = v.u;
    return (short)((u + 0x7fffu + ((u >> 16) & 1u)) >> 16);
}

// Parallel first-occurrence scatter, 4 nodes/thread via int4.
// batch sorted; first_idx[b] = i iff (i==0 || batch[i-1] != batch[i]).
__global__ __launch_bounds__(256) void first_occ_kernel(
        const int* __restrict__ batch, int* __restrict__ fidx) {
    const int i4 = blockIdx.x * blockDim.x + threadIdx.x;   // quad index
    const int base = i4 * 4;
    const int4 v = *reinterpret_cast<const int4*>(batch + base);
    const int prev = (base == 0) ? -1 : batch[base - 1];    // cache-hit peek
    if (v.x != prev && (unsigned)v.x < NUM_GRAPHS) fidx[v.x] = base;
    if (v.y != v.x  && (unsigned)v.y < NUM_GRAPHS) fidx[v.y] = base + 1;
    if (v.z != v.y  && (unsigned)v.z < NUM_GRAPHS) fidx[v.z] = base + 2;
    if (v.w != v.z  && (unsigned)v.w < NUM_GRAPHS) fidx[v.w] = base + 3;
}

// One wave per (16 graphs x 32 cols). grid = CSPLIT*GGROUPS blocks of 64.
// bid = ct*GGROUPS + g  ->  bid%8 == g%8: all col-splits of a graph-group land on
// the same XCD, so the gathered x rows are fetched into that XCD's L2 once.
__global__ __launch_bounds__(64) void pool_linear_kernel(
        const float* __restrict__ x, const float* __restrict__ W,
        const float* __restrict__ bias, const int* __restrict__ fidx,
        float* __restrict__ out) {
    const int bid = blockIdx.x;
    const int gg  = bid & (GGROUPS - 1);   // graph-group
    const int cth = bid >> 9;              // 0..3 -> col-tiles 2*cth, 2*cth+1

    const int l  = threadIdx.x;
    const int r  = l & 15;   // A-row / B-col / D-col within tile
    const int kg = l >> 4;   // k-group
    const int gbase = gg * 16;

    // A fragments: gathered row of x -> bf16. Loaded once, reused for both col-tiles.
    const int fi = fidx[gbase + r];
    const float* xrow = x + (size_t)fi * C;
    bf16x8 a[4];
#pragma unroll
    for (int kc = 0; kc < 4; ++kc) {
        const int k0 = kc * 32 + kg * 8;
        const float4 lo = *reinterpret_cast<const float4*>(xrow + k0);
        const float4 hi = *reinterpret_cast<const float4*>(xrow + k0 + 4);
        a[kc][0] = f2bf(lo.x); a[kc][1] = f2bf(lo.y); a[kc][2] = f2bf(lo.z); a[kc][3] = f2bf(lo.w);
        a[kc][4] = f2bf(hi.x); a[kc][5] = f2bf(hi.y); a[kc][6] = f2bf(hi.z); a[kc][7] = f2bf(hi.w);
    }

#pragma unroll
    for (int t = 0; t < 2; ++t) {
        const int ct  = cth * 2 + t;
        const int col = ct * 16 + r;                 // B col = D col = lane&15
        const float* wrow = W + (size_t)col * C;     // out[g][col] = sum_k x[fi][k]*W[col][k]
        const float bc = bias[col];
        f32x4 acc = {bc, bc, bc, bc};
#pragma unroll
        for (int kc = 0; kc < 4; ++kc) {
            const int k0 = kc * 32 + kg * 8;
            const float4 lo = *reinterpret_cast<const float4*>(wrow + k0);
            const float4 hi = *reinterpret_cast<const float4*>(wrow + k0 + 4);
            bf16x8 bf;
            bf[0] = f2bf(lo.x); bf[1] = f2bf(lo.y); bf[2] = f2bf(lo.z); bf[3] = f2bf(lo.w);
            bf[4] = f2bf(hi.x); bf[5] = f2bf(hi.y); bf[6] = f2bf(hi.z); bf[7] = f2bf(hi.w);
            acc = __builtin_amdgcn_mfma_f32_16x16x32_bf16(a[kc], bf, acc, 0, 0, 0);
        }
        // C/D layout: col = lane&15, row = (lane>>4)*4 + reg
#pragma unroll
        for (int reg = 0; reg < 4; ++reg) {
            const int row = gbase + kg * 4 + reg;
            out[(size_t)row * C + col] = acc[reg];
        }
    }
}

extern "C" void kernel_launch(void* const* d_in, const int* in_sizes, int n_in,
                              void* d_out, int out_size, void* d_ws, size_t ws_size,
                              hipStream_t stream) {
    const float* x     = (const float*)d_in[0];
    const int*   batch = (const int*)d_in[1];
    const float* W     = (const float*)d_in[2];
    const float* b     = (const float*)d_in[3];
    float*       out   = (float*)d_out;
    int*         fidx  = (int*)d_ws;   // NUM_GRAPHS ints = 32 KB scratch

    first_occ_kernel<<<TOTAL_NODES / 4 / 256, 256, 0, stream>>>(batch, fidx);
    pool_linear_kernel<<<CSPLIT * GGROUPS, 64, 0, stream>>>(x, W, b, fidx, out);
}

// Round 3
// 13.268 us; speedup vs baseline: 1.2697x; 1.2697x over previous
//
#include <hip/hip_runtime.h>
#include <stdint.h>

#define NUM_GRAPHS 8192
#define NODES_PER_GRAPH 128
#define TOTAL_NODES (NUM_GRAPHS * NODES_PER_GRAPH)
#define C 128
#define GGROUPS (NUM_GRAPHS / 16)   // 512 graph-groups of 16
#define CSPLIT 4                    // each wave does 2 of the 8 col-tiles

typedef __attribute__((ext_vector_type(8))) short bf16x8;
typedef __attribute__((ext_vector_type(4))) float f32x4;

// f32 -> bf16 bits, round-to-nearest-even
static __device__ __forceinline__ short f2bf(float f) {
    union { float f; uint32_t u; } v; v.f = f;
    const uint32_t u = v.u;
    return (short)((u + 0x7fffu + ((u >> 16) & 1u)) >> 16);
}

// First occurrence of graph g in sorted `batch`. Fast path: uniform guess
// g*(TOTAL/NUM) verified with 2 cached loads (exact for this input).
// Fallback: lower_bound binary search (correct for any sorted batch with all
// graph ids present).
static __device__ __forceinline__ int first_index(const int* __restrict__ batch, int g) {
    const int p = g * (TOTAL_NODES / NUM_GRAPHS);
    if (batch[p] == g && (p == 0 || batch[p - 1] < g)) return p;
    int lo = 0, hi = TOTAL_NODES;
    while (lo < hi) {
        const int mid = (lo + hi) >> 1;
        if (batch[mid] < g) lo = mid + 1; else hi = mid;
    }
    return lo;
}

// Fused: one wave per (16 graphs x 32 cols). grid = CSPLIT*GGROUPS blocks of 64.
// bid%GGROUPS = graph-group -> all col-splits of a group share bid%8 (same XCD),
// so gathered x rows are fetched into that XCD's L2 once.
__global__ __launch_bounds__(64) void pool_linear_fused(
        const float* __restrict__ x, const int* __restrict__ batch,
        const float* __restrict__ W, const float* __restrict__ bias,
        float* __restrict__ out) {
    const int bid = blockIdx.x;
    const int gg  = bid & (GGROUPS - 1);   // graph-group
    const int cth = bid >> 9;              // 0..3 -> col-tiles 2*cth, 2*cth+1

    const int l  = threadIdx.x;
    const int r  = l & 15;   // A-row / B-col / D-col within tile
    const int kg = l >> 4;   // k-group
    const int gbase = gg * 16;

    // Per-lane first-node index (2 cached loads on the fast path).
    const int fi = first_index(batch, gbase + r);

    // A fragments: gathered row of x -> bf16. Loaded once, reused for both col-tiles.
    const float* xrow = x + (size_t)fi * C;
    bf16x8 a[4];
#pragma unroll
    for (int kc = 0; kc < 4; ++kc) {
        const int k0 = kc * 32 + kg * 8;
        const float4 lo = *reinterpret_cast<const float4*>(xrow + k0);
        const float4 hi = *reinterpret_cast<const float4*>(xrow + k0 + 4);
        a[kc][0] = f2bf(lo.x); a[kc][1] = f2bf(lo.y); a[kc][2] = f2bf(lo.z); a[kc][3] = f2bf(lo.w);
        a[kc][4] = f2bf(hi.x); a[kc][5] = f2bf(hi.y); a[kc][6] = f2bf(hi.z); a[kc][7] = f2bf(hi.w);
    }

#pragma unroll
    for (int t = 0; t < 2; ++t) {
        const int ct  = cth * 2 + t;
        const int col = ct * 16 + r;                 // B col = D col = lane&15
        const float* wrow = W + (size_t)col * C;     // out[g][col] = sum_k x[fi][k]*W[col][k]
        const float bc = bias[col];
        f32x4 acc = {bc, bc, bc, bc};
#pragma unroll
        for (int kc = 0; kc < 4; ++kc) {
            const int k0 = kc * 32 + kg * 8;
            const float4 lo = *reinterpret_cast<const float4*>(wrow + k0);
            const float4 hi = *reinterpret_cast<const float4*>(wrow + k0 + 4);
            bf16x8 bf;
            bf[0] = f2bf(lo.x); bf[1] = f2bf(lo.y); bf[2] = f2bf(lo.z); bf[3] = f2bf(lo.w);
            bf[4] = f2bf(hi.x); bf[5] = f2bf(hi.y); bf[6] = f2bf(hi.z); bf[7] = f2bf(hi.w);
            acc = __builtin_amdgcn_mfma_f32_16x16x32_bf16(a[kc], bf, acc, 0, 0, 0);
        }
        // C/D layout: col = lane&15, row = (lane>>4)*4 + reg
#pragma unroll
        for (int reg = 0; reg < 4; ++reg) {
            const int row = gbase + kg * 4 + reg;
            out[(size_t)row * C + col] = acc[reg];
        }
    }
}

extern "C" void kernel_launch(void* const* d_in, const int* in_sizes, int n_in,
                              void* d_out, int out_size, void* d_ws, size_t ws_size,
                              hipStream_t stream) {
    const float* x     = (const float*)d_in[0];
    const int*   batch = (const int*)d_in[1];
    const float* W     = (const float*)d_in[2];
    const float* b     = (const float*)d_in[3];
    float*       out   = (float*)d_out;

    pool_linear_fused<<<CSPLIT * GGROUPS, 64, 0, stream>>>(x, batch, W, b, out);
}